// Round 9
// baseline (264.606 us; speedup 1.0000x reference)
//
#include <hip/hip_runtime.h>

#define NTOK 1024
#define KSEL 256

// Workspace (floats):
//   Ppart [NS][B][2][33][NTOK] : per-channel-split partial projections.
//     part0 (xt): j0 = gx.xt (score_x), j1..8 = px@xt, j9..16 = pm@xt,
//                 j17..24 = prx@xt, j25..32 = prm@xt
//     part1 (mt): j0 = gm.mt (score_m), j1..8 = px@mt, j9..16 = pm@mt,
//                 j17..24 = prx@mt, j25..32 = prm@mt
//   masks [B][4][NTOK] : tm_x, rm_x, tm_m, rm_m (binary 0/1)
//   G     [B][8][NTOK] : fuse_x + fuse_m per token

// ---------------- K1: skinny projection ----------------
// J-split (rows 0..16 / 17..32 in separate blocks) keeps acc[<=17] float4
// (~68 VGPR, no spill — R8's acc[33]=132 spilled at VGPR_Count=84) and
// doubles grid to 2048 blocks (16 waves/CU). LDS-staged weights read as
// wave-uniform ds_read_b128 (0 conflicts, verified R6); 4 tokens/thread
// so each ds_read feeds 16 FMA.
template <int NS, int JB, int NJ>
__device__ __forceinline__ void k1_body(
    const float* __restrict__ xp, const float* __restrict__ gw,
    const float* __restrict__ px_w, const float* __restrict__ pm_w,
    const float* __restrict__ prx_w, const float* __restrict__ prm_w,
    float* __restrict__ wlds, float* __restrict__ op, int cw0, int tid)
{
  constexpr int CS = 384 / NS;
  for (int idx = tid; idx < NJ * CS; idx += 128) {
    int jr = idx / CS;
    int c = idx - jr * CS;
    int j = JB + jr;
    const float* src;
    if (j == 0)       src = gw;
    else if (j < 9)   src = px_w  + (j - 1)  * 384;
    else if (j < 17)  src = pm_w  + (j - 9)  * 384;
    else if (j < 25)  src = prx_w + (j - 17) * 384;
    else              src = prm_w + (j - 25) * 384;
    wlds[idx] = src[cw0 + c];
  }
  __syncthreads();

  float4 acc[NJ];
  #pragma unroll
  for (int j = 0; j < NJ; ++j) acc[j] = make_float4(0.f, 0.f, 0.f, 0.f);

  #pragma unroll 2
  for (int c4 = 0; c4 < CS / 4; ++c4) {
    float4 v0 = *reinterpret_cast<const float4*>(xp + (size_t)(c4 * 4 + 0) * NTOK);
    float4 v1 = *reinterpret_cast<const float4*>(xp + (size_t)(c4 * 4 + 1) * NTOK);
    float4 v2 = *reinterpret_cast<const float4*>(xp + (size_t)(c4 * 4 + 2) * NTOK);
    float4 v3 = *reinterpret_cast<const float4*>(xp + (size_t)(c4 * 4 + 3) * NTOK);
    #pragma unroll
    for (int j = 0; j < NJ; ++j) {
      float4 w = *reinterpret_cast<const float4*>(&wlds[j * CS + c4 * 4]);
      acc[j].x = fmaf(w.x, v0.x, fmaf(w.y, v1.x, fmaf(w.z, v2.x, fmaf(w.w, v3.x, acc[j].x))));
      acc[j].y = fmaf(w.x, v0.y, fmaf(w.y, v1.y, fmaf(w.z, v2.y, fmaf(w.w, v3.y, acc[j].y))));
      acc[j].z = fmaf(w.x, v0.z, fmaf(w.y, v1.z, fmaf(w.z, v2.z, fmaf(w.w, v3.z, acc[j].z))));
      acc[j].w = fmaf(w.x, v0.w, fmaf(w.y, v1.w, fmaf(w.z, v2.w, fmaf(w.w, v3.w, acc[j].w))));
    }
  }
  #pragma unroll
  for (int j = 0; j < NJ; ++j)
    *reinterpret_cast<float4*>(op + (size_t)(JB + j) * NTOK) = acc[j];
}

// grid bits: part(1) | ntile(1) | jh(1) | s(log2 NS) | b(5); block = 128.
template <int NS>
__global__ __launch_bounds__(128, 4) void k1_proj(
    const float* __restrict__ x,
    const float* __restrict__ gx_w, const float* __restrict__ gm_w,
    const float* __restrict__ px_w, const float* __restrict__ pm_w,
    const float* __restrict__ prx_w, const float* __restrict__ prm_w,
    float* __restrict__ Pp)
{
  constexpr int CS = 384 / NS;
  constexpr int L2NS = (NS == 8) ? 3 : 2;
  __shared__ float wlds[17 * CS];

  int blk = blockIdx.x;
  int part = blk & 1;
  int ntile = (blk >> 1) & 1;          // 2 tiles of 512 tokens
  int jh = (blk >> 2) & 1;
  int s = (blk >> 3) & (NS - 1);
  int b = blk >> (3 + L2NS);
  int n0 = ntile * 512 + threadIdx.x * 4;
  const float* gw = part ? gm_w : gx_w;
  int cw0 = s * CS;

  const float* xp = x + ((size_t)b * 768 + part * 384 + cw0) * NTOK + n0;
  float* op = Pp + ((((size_t)s * 32 + b) * 2 + part) * 33) * NTOK + n0;

  if (jh == 0)
    k1_body<NS, 0, 17>(xp, gw, px_w, pm_w, prx_w, prm_w, wlds, op, cw0, threadIdx.x);
  else
    k1_body<NS, 17, 16>(xp, gw, px_w, pm_w, prx_w, prm_w, wlds, op, cw0, threadIdx.x);
}

// ---------------- K2: exact stable top-k & bottom-k, one wave per row ----------------
// grid = 64 blocks (32 b x 2 branches), block = 64. Scores in registers.
__global__ __launch_bounds__(64) void k2_masks(
    const float* __restrict__ Ppart, float* __restrict__ masks, int nsplit)
{
  int b = blockIdx.x >> 1;
  int branch = blockIdx.x & 1;
  int lane = threadIdx.x;
  unsigned long long lmask = (1ull << lane) - 1ull;

  float v[16];
  #pragma unroll
  for (int i = 0; i < 16; ++i) v[i] = 0.f;
  for (int s = 0; s < nsplit; ++s) {
    const float* sp = Ppart + (((size_t)s * 32 + b) * 2 + branch) * 33 * NTOK;
    #pragma unroll
    for (int i = 0; i < 16; ++i) v[i] += sp[i * 64 + lane];
  }
  unsigned key[16];
  #pragma unroll
  for (int i = 0; i < 16; ++i) {
    float f = v[i] + 0.0f;  // canonicalize -0.0
    unsigned bits = __float_as_uint(f);
    key[i] = (bits & 0x80000000u) ? ~bits : (bits | 0x80000000u);
  }

  for (int which = 0; which < 2; ++which) {
    unsigned prefix = 0u;
    for (int bit = 31; bit >= 0; --bit) {
      unsigned cand = prefix | (1u << bit);
      int cnt = 0;
      #pragma unroll
      for (int i = 0; i < 16; ++i) {
        unsigned kk = which ? ~key[i] : key[i];
        cnt += __popcll(__ballot(kk >= cand));
      }
      if (cnt >= KSEL) prefix = cand;
    }
    int cgt = 0;
    #pragma unroll
    for (int i = 0; i < 16; ++i) {
      unsigned kk = which ? ~key[i] : key[i];
      cgt += __popcll(__ballot(kk > prefix));
    }
    int quota = KSEL - cgt;
    float* mp = masks + ((size_t)b * 4 + branch * 2 + which) * NTOK;
    int run = 0;
    #pragma unroll
    for (int i = 0; i < 16; ++i) {
      unsigned kk = which ? ~key[i] : key[i];
      bool eq = (kk == prefix);
      unsigned long long bal = __ballot(eq);
      int rank = run + __popcll(bal & lmask);
      bool sel = (kk > prefix) || (eq && rank < quota);
      mp[i * 64 + lane] = sel ? 1.0f : 0.0f;
      run += __popcll(bal);
    }
  }
}

// ---------------- K3g: split-sum + mask + fuse matmul -> G ----------------
// grid = 32 b * 16 tiles = 512 blocks, block = 256 = (tok 64) x (kind 4).
template <int NS>
__global__ __launch_bounds__(256) void k3g(
    const float* __restrict__ Ppart, const float* __restrict__ masks,
    const float* __restrict__ px_b, const float* __restrict__ pm_b,
    const float* __restrict__ prx_b, const float* __restrict__ prm_b,
    const float* __restrict__ pfx_w, const float* __restrict__ pfx_b,
    const float* __restrict__ pfm_w, const float* __restrict__ pfm_b,
    float* __restrict__ G)
{
  __shared__ float lows[32][64];  // [kind*8+r][tok]
  int tile = blockIdx.x & 15;
  int b = blockIdx.x >> 4;
  int t = threadIdx.x;
  int tok = t & 63;
  int kind = t >> 6;              // wave-uniform: 0=lowx 1=lrx 2=lowm 3=lrm
  int n = tile * 64 + tok;

  int branch = kind >> 1;
  const float* mk = masks + ((size_t)b * 4 + branch * 2) * NTOK + n;
  float tm = mk[0];
  float rm = mk[NTOK];
  int rowbase = (kind == 0) ? 1 : (kind == 1) ? 17 : (kind == 2) ? 9 : 25;

  #pragma unroll
  for (int r = 0; r < 8; ++r) {
    float s0 = 0.f, s1 = 0.f;
    #pragma unroll
    for (int sp = 0; sp < NS; ++sp) {
      const float* P0 = Ppart + (((size_t)sp * 32 + b) * 2 + 0) * 33 * NTOK + n;
      const float* P1 = Ppart + (((size_t)sp * 32 + b) * 2 + 1) * 33 * NTOK + n;
      s0 += P0[(size_t)(rowbase + r) * NTOK];
      s1 += P1[(size_t)(rowbase + r) * NTOK];
    }
    float val;
    if (kind == 0)      val = fmaf(tm, s0, fmaf(rm, s1, px_b[r]));   // low_x
    else if (kind == 2) val = fmaf(tm, s1, fmaf(rm, s0, pm_b[r]));   // low_m
    else {
      float w = 1.0f - tm - rm;
      val = fmaf(w, s0 + s1, (kind == 1) ? prx_b[r] : prm_b[r]);     // low_res
    }
    lows[kind * 8 + r][tok] = val;
  }
  __syncthreads();

  if (t < 64) {
    float L[32];
    #pragma unroll
    for (int i = 0; i < 32; ++i) L[i] = lows[i][tok];
    #pragma unroll
    for (int r = 0; r < 8; ++r) {
      float acc = pfx_b[r] + pfm_b[r];
      #pragma unroll
      for (int s2 = 0; s2 < 8; ++s2) {
        acc = fmaf(pfx_w[r * 16 + s2],     L[s2],      acc);
        acc = fmaf(pfx_w[r * 16 + 8 + s2], L[8 + s2],  acc);
        acc = fmaf(pfm_w[r * 16 + s2],     L[16 + s2], acc);
        acc = fmaf(pfm_w[r * 16 + 8 + s2], L[24 + s2], acc);
      }
      G[((size_t)b * 8 + r) * NTOK + n] = acc;
    }
  }
}

// ---------------- K4: rank-8 -> 384 expansion ----------------
// grid = 32 b * 8 cparts * 4 ttiles = 1024 blocks (4096 waves), block = 256.
__global__ __launch_bounds__(256) void k4_out(
    const float* __restrict__ G, const float* __restrict__ pb_w,
    const float* __restrict__ pb_b, float* __restrict__ out)
{
  __shared__ float wl[48 * 8 + 48];
  int blk = blockIdx.x;
  int ttile = blk & 3;          // 4 tiles of 256 tokens
  int cpart = (blk >> 2) & 7;   // 8 chunks of 48 channels
  int b = blk >> 5;
  int c0 = cpart * 48;

  for (int idx = threadIdx.x; idx < 48 * 8 + 48; idx += 256)
    wl[idx] = (idx < 384) ? pb_w[(size_t)c0 * 8 + idx] : pb_b[c0 + idx - 384];
  __syncthreads();

  int n = ttile * 256 + threadIdx.x;
  float g[8];
  #pragma unroll
  for (int r = 0; r < 8; ++r) g[r] = G[((size_t)b * 8 + r) * NTOK + n];

  float* op = out + ((size_t)b * 384 + c0) * NTOK + n;
  #pragma unroll 4
  for (int c = 0; c < 48; ++c) {
    float4 w0 = *reinterpret_cast<const float4*>(&wl[c * 8]);
    float4 w1 = *reinterpret_cast<const float4*>(&wl[c * 8 + 4]);
    float acc = wl[384 + c];
    acc = fmaf(w0.x, g[0], acc);
    acc = fmaf(w0.y, g[1], acc);
    acc = fmaf(w0.z, g[2], acc);
    acc = fmaf(w0.w, g[3], acc);
    acc = fmaf(w1.x, g[4], acc);
    acc = fmaf(w1.y, g[5], acc);
    acc = fmaf(w1.z, g[6], acc);
    acc = fmaf(w1.w, g[7], acc);
    op[(size_t)c * NTOK] = acc;
  }
}

extern "C" void kernel_launch(void* const* d_in, const int* in_sizes, int n_in,
                              void* d_out, int out_size, void* d_ws, size_t ws_size,
                              hipStream_t stream) {
  const float* x     = (const float*)d_in[0];
  const float* gx_w  = (const float*)d_in[1];
  const float* gm_w  = (const float*)d_in[3];
  const float* px_w  = (const float*)d_in[5];
  const float* px_b  = (const float*)d_in[6];
  const float* pm_w  = (const float*)d_in[7];
  const float* pm_b  = (const float*)d_in[8];
  const float* prx_w = (const float*)d_in[9];
  const float* prx_b = (const float*)d_in[10];
  const float* prm_w = (const float*)d_in[11];
  const float* prm_b = (const float*)d_in[12];
  const float* pfx_w = (const float*)d_in[13];
  const float* pfx_b = (const float*)d_in[14];
  const float* pfm_w = (const float*)d_in[15];
  const float* pfm_b = (const float*)d_in[16];
  const float* pb_w  = (const float*)d_in[17];
  const float* pb_b  = (const float*)d_in[18];
  float* out = (float*)d_out;

  const size_t P1_F   = 32ull * 2 * 33 * NTOK;  // one split slab (floats)
  const size_t MASK_F = 32ull * 4 * NTOK;
  const size_t G_F    = 32ull * 8 * NTOK;
  const size_t need8  = (8 * P1_F + MASK_F + G_F) * 4;
  const size_t need4  = (4 * P1_F + MASK_F + G_F) * 4;

  float* ws = (float*)d_ws;
  if (ws_size >= need8) {
    float* Ppart = ws;
    float* masks = ws + 8 * P1_F;
    float* G     = masks + MASK_F;
    k1_proj<8><<<2048, 128, 0, stream>>>(x, gx_w, gm_w, px_w, pm_w, prx_w, prm_w, Ppart);
    k2_masks<<<64, 64, 0, stream>>>(Ppart, masks, 8);
    k3g<8><<<512, 256, 0, stream>>>(Ppart, masks, px_b, pm_b, prx_b, prm_b,
                                    pfx_w, pfx_b, pfm_w, pfm_b, G);
    k4_out<<<1024, 256, 0, stream>>>(G, pb_w, pb_b, out);
  } else {
    float* Ppart = ws;
    float* masks = ws + 4 * P1_F;
    float* G     = masks + MASK_F;
    k1_proj<4><<<1024, 128, 0, stream>>>(x, gx_w, gm_w, px_w, pm_w, prx_w, prm_w, Ppart);
    k2_masks<<<64, 64, 0, stream>>>(Ppart, masks, 4);
    k3g<4><<<512, 256, 0, stream>>>(Ppart, masks, px_b, pm_b, prx_b, prm_b,
                                    pfx_w, pfx_b, pfm_w, pfm_b, G);
    k4_out<<<1024, 256, 0, stream>>>(G, pb_w, pb_b, out);
  }
}

// Round 10
// 258.980 us; speedup vs baseline: 1.0217x; 1.0217x over previous
//
#include <hip/hip_runtime.h>

#define NTOK 1024
#define KSEL 256

// Workspace (floats):
//   Ppart [4][B][2][33][NTOK] : per-channel-split partial projections (NS=4).
//     part0 (xt): j0 = gx.xt (score_x), j1..8 = px@xt, j9..16 = pm@xt,
//                 j17..24 = prx@xt, j25..32 = prm@xt
//     part1 (mt): j0 = gm.mt (score_m), j1..8 = px@mt, ...
//   masks [B][4][NTOK] : tm_x, rm_x, tm_m, rm_m (binary 0/1)

#define NS 4
#define CS 96  // 384 / NS

// ---------------- K1: skinny projection ----------------
// 4 tokens/thread (float4), all 33 rows per thread, NS=4 channel split.
// Weights staged in LDS, read as wave-uniform ds_read_b128 (0 conflicts,
// verified R6). LDS-issue cost = waves*792*12cyc/CU: at 4 waves/CU -> 16us.
// __launch_bounds__(256,1): 512-VGPR budget so acc[33] float4 (132 VGPR)
// does NOT spill (R8's (128,2)=256 cap made the compiler mangle it at 84).
// grid = 32b * 2part * 4s = 256 blocks, block = 256 (covers all 1024 tokens).
__global__ __launch_bounds__(256, 1) void k1_proj(
    const float* __restrict__ x,
    const float* __restrict__ gx_w, const float* __restrict__ gm_w,
    const float* __restrict__ px_w, const float* __restrict__ pm_w,
    const float* __restrict__ prx_w, const float* __restrict__ prm_w,
    float* __restrict__ Pp)
{
  __shared__ float wlds[33 * CS];  // 12.7 KB

  int blk = blockIdx.x;
  int part = blk & 1;
  int s = (blk >> 1) & (NS - 1);
  int b = blk >> 3;
  int n0 = threadIdx.x * 4;
  const float* gw = part ? gm_w : gx_w;
  int cw0 = s * CS;

  for (int idx = threadIdx.x; idx < 33 * CS; idx += 256) {
    int j = idx / CS;
    int c = idx - j * CS;
    const float* src;
    if (j == 0)       src = gw;
    else if (j < 9)   src = px_w  + (j - 1)  * 384;
    else if (j < 17)  src = pm_w  + (j - 9)  * 384;
    else if (j < 25)  src = prx_w + (j - 17) * 384;
    else              src = prm_w + (j - 25) * 384;
    wlds[idx] = src[cw0 + c];
  }
  __syncthreads();

  float4 acc[33];
  #pragma unroll
  for (int j = 0; j < 33; ++j) acc[j] = make_float4(0.f, 0.f, 0.f, 0.f);

  const float* xp = x + ((size_t)b * 768 + part * 384 + cw0) * NTOK + n0;
  for (int c4 = 0; c4 < CS / 4; ++c4) {
    float4 v0 = *reinterpret_cast<const float4*>(xp + (size_t)(c4 * 4 + 0) * NTOK);
    float4 v1 = *reinterpret_cast<const float4*>(xp + (size_t)(c4 * 4 + 1) * NTOK);
    float4 v2 = *reinterpret_cast<const float4*>(xp + (size_t)(c4 * 4 + 2) * NTOK);
    float4 v3 = *reinterpret_cast<const float4*>(xp + (size_t)(c4 * 4 + 3) * NTOK);
    #pragma unroll
    for (int j = 0; j < 33; ++j) {
      float4 w = *reinterpret_cast<const float4*>(&wlds[j * CS + c4 * 4]);
      acc[j].x = fmaf(w.x, v0.x, fmaf(w.y, v1.x, fmaf(w.z, v2.x, fmaf(w.w, v3.x, acc[j].x))));
      acc[j].y = fmaf(w.x, v0.y, fmaf(w.y, v1.y, fmaf(w.z, v2.y, fmaf(w.w, v3.y, acc[j].y))));
      acc[j].z = fmaf(w.x, v0.z, fmaf(w.y, v1.z, fmaf(w.z, v2.z, fmaf(w.w, v3.z, acc[j].z))));
      acc[j].w = fmaf(w.x, v0.w, fmaf(w.y, v1.w, fmaf(w.z, v2.w, fmaf(w.w, v3.w, acc[j].w))));
    }
  }
  float* op = Pp + ((((size_t)s * 32 + b) * 2 + part) * 33) * NTOK + n0;
  #pragma unroll
  for (int j = 0; j < 33; ++j)
    *reinterpret_cast<float4*>(op + (size_t)j * NTOK) = acc[j];
}

// ---------------- K2: exact stable top-k & bottom-k, one wave per row ----------------
// grid = 64 blocks (32 b x 2 branches), block = 64. Scores in registers.
__global__ __launch_bounds__(64) void k2_masks(
    const float* __restrict__ Ppart, float* __restrict__ masks)
{
  int b = blockIdx.x >> 1;
  int branch = blockIdx.x & 1;
  int lane = threadIdx.x;
  unsigned long long lmask = (1ull << lane) - 1ull;

  float v[16];
  #pragma unroll
  for (int i = 0; i < 16; ++i) v[i] = 0.f;
  #pragma unroll
  for (int s = 0; s < NS; ++s) {
    const float* sp = Ppart + (((size_t)s * 32 + b) * 2 + branch) * 33 * NTOK;
    #pragma unroll
    for (int i = 0; i < 16; ++i) v[i] += sp[i * 64 + lane];
  }
  unsigned key[16];
  #pragma unroll
  for (int i = 0; i < 16; ++i) {
    float f = v[i] + 0.0f;  // canonicalize -0.0
    unsigned bits = __float_as_uint(f);
    key[i] = (bits & 0x80000000u) ? ~bits : (bits | 0x80000000u);
  }

  for (int which = 0; which < 2; ++which) {
    unsigned prefix = 0u;
    for (int bit = 31; bit >= 0; --bit) {
      unsigned cand = prefix | (1u << bit);
      int cnt = 0;
      #pragma unroll
      for (int i = 0; i < 16; ++i) {
        unsigned kk = which ? ~key[i] : key[i];
        cnt += __popcll(__ballot(kk >= cand));
      }
      if (cnt >= KSEL) prefix = cand;
    }
    int cgt = 0;
    #pragma unroll
    for (int i = 0; i < 16; ++i) {
      unsigned kk = which ? ~key[i] : key[i];
      cgt += __popcll(__ballot(kk > prefix));
    }
    int quota = KSEL - cgt;
    float* mp = masks + ((size_t)b * 4 + branch * 2 + which) * NTOK;
    int run = 0;
    #pragma unroll
    for (int i = 0; i < 16; ++i) {
      unsigned kk = which ? ~key[i] : key[i];
      bool eq = (kk == prefix);
      unsigned long long bal = __ballot(eq);
      int rank = run + __popcll(bal & lmask);
      bool sel = (kk > prefix) || (eq && rank < quota);
      mp[i * 64 + lane] = sel ? 1.0f : 0.0f;
      run += __popcll(bal);
    }
  }
}

// ---------------- K3f: fused split-sum + mask + fuse matmul + 384 expansion ----------------
// grid = 32 b * 16 tiles (64 tokens) = 512 blocks, block = 256 = (tok 64) x (kind 4).
// P1: thread (tok,kind) computes 8 lows -> LDS (64 independent coalesced loads).
// P2: wave 0 does the 8x32 fuse matmul -> g -> LDS.
// P3: thread (tok,cpart=kind) expands 96 output channels, pb_w LDS-staged.
__global__ __launch_bounds__(256) void k3f(
    const float* __restrict__ Ppart, const float* __restrict__ masks,
    const float* __restrict__ px_b, const float* __restrict__ pm_b,
    const float* __restrict__ prx_b, const float* __restrict__ prm_b,
    const float* __restrict__ pfx_w, const float* __restrict__ pfx_b,
    const float* __restrict__ pfm_w, const float* __restrict__ pfm_b,
    const float* __restrict__ pb_w, const float* __restrict__ pb_b,
    float* __restrict__ out)
{
  __shared__ float lows[32][64];   // [kind*8+r][tok]
  __shared__ float gl[8][64];      // [r][tok]
  __shared__ float wl[384 * 8 + 384];  // pb_w + pb_b, 13.9 KB
  int tile = blockIdx.x & 15;
  int b = blockIdx.x >> 4;
  int t = threadIdx.x;
  int tok = t & 63;
  int kind = t >> 6;               // wave-uniform
  int n = tile * 64 + tok;

  // stage pb_w / pb_b while P1's global loads are in flight
  for (int idx = t; idx < 384 * 8 + 384; idx += 256)
    wl[idx] = (idx < 384 * 8) ? pb_w[idx] : pb_b[idx - 384 * 8];

  // ---- P1 ----
  int branch = kind >> 1;
  const float* mk = masks + ((size_t)b * 4 + branch * 2) * NTOK + n;
  float tm = mk[0];
  float rm = mk[NTOK];
  int rowbase = (kind == 0) ? 1 : (kind == 1) ? 17 : (kind == 2) ? 9 : 25;

  #pragma unroll
  for (int r = 0; r < 8; ++r) {
    float s0 = 0.f, s1 = 0.f;
    #pragma unroll
    for (int sp = 0; sp < NS; ++sp) {
      const float* P0 = Ppart + (((size_t)sp * 32 + b) * 2 + 0) * 33 * NTOK + n;
      const float* P1 = Ppart + (((size_t)sp * 32 + b) * 2 + 1) * 33 * NTOK + n;
      s0 += P0[(size_t)(rowbase + r) * NTOK];
      s1 += P1[(size_t)(rowbase + r) * NTOK];
    }
    float val;
    if (kind == 0)      val = fmaf(tm, s0, fmaf(rm, s1, px_b[r]));   // low_x
    else if (kind == 2) val = fmaf(tm, s1, fmaf(rm, s0, pm_b[r]));   // low_m
    else {
      float w = 1.0f - tm - rm;
      val = fmaf(w, s0 + s1, (kind == 1) ? prx_b[r] : prm_b[r]);     // low_res
    }
    lows[kind * 8 + r][tok] = val;
  }
  __syncthreads();

  // ---- P2 ----
  if (t < 64) {
    float L[32];
    #pragma unroll
    for (int i = 0; i < 32; ++i) L[i] = lows[i][tok];
    #pragma unroll
    for (int r = 0; r < 8; ++r) {
      float acc = pfx_b[r] + pfm_b[r];
      #pragma unroll
      for (int s2 = 0; s2 < 8; ++s2) {
        acc = fmaf(pfx_w[r * 16 + s2],     L[s2],      acc);
        acc = fmaf(pfx_w[r * 16 + 8 + s2], L[8 + s2],  acc);
        acc = fmaf(pfm_w[r * 16 + s2],     L[16 + s2], acc);
        acc = fmaf(pfm_w[r * 16 + 8 + s2], L[24 + s2], acc);
      }
      gl[r][tok] = acc;
    }
  }
  __syncthreads();

  // ---- P3 ----
  float g[8];
  #pragma unroll
  for (int r = 0; r < 8; ++r) g[r] = gl[r][tok];

  int c0 = kind * 96;
  float* op = out + ((size_t)b * 384 + c0) * NTOK + n;
  #pragma unroll 4
  for (int c = 0; c < 96; ++c) {
    float4 w0 = *reinterpret_cast<const float4*>(&wl[(c0 + c) * 8]);
    float4 w1 = *reinterpret_cast<const float4*>(&wl[(c0 + c) * 8 + 4]);
    float acc = wl[384 * 8 + c0 + c];
    acc = fmaf(w0.x, g[0], acc);
    acc = fmaf(w0.y, g[1], acc);
    acc = fmaf(w0.z, g[2], acc);
    acc = fmaf(w0.w, g[3], acc);
    acc = fmaf(w1.x, g[4], acc);
    acc = fmaf(w1.y, g[5], acc);
    acc = fmaf(w1.z, g[6], acc);
    acc = fmaf(w1.w, g[7], acc);
    op[(size_t)c * NTOK] = acc;
  }
}

extern "C" void kernel_launch(void* const* d_in, const int* in_sizes, int n_in,
                              void* d_out, int out_size, void* d_ws, size_t ws_size,
                              hipStream_t stream) {
  const float* x     = (const float*)d_in[0];
  const float* gx_w  = (const float*)d_in[1];
  const float* gm_w  = (const float*)d_in[3];
  const float* px_w  = (const float*)d_in[5];
  const float* px_b  = (const float*)d_in[6];
  const float* pm_w  = (const float*)d_in[7];
  const float* pm_b  = (const float*)d_in[8];
  const float* prx_w = (const float*)d_in[9];
  const float* prx_b = (const float*)d_in[10];
  const float* prm_w = (const float*)d_in[11];
  const float* prm_b = (const float*)d_in[12];
  const float* pfx_w = (const float*)d_in[13];
  const float* pfx_b = (const float*)d_in[14];
  const float* pfm_w = (const float*)d_in[15];
  const float* pfm_b = (const float*)d_in[16];
  const float* pb_w  = (const float*)d_in[17];
  const float* pb_b  = (const float*)d_in[18];
  float* out = (float*)d_out;

  const size_t P1_F   = 32ull * 2 * 33 * NTOK;  // one split slab (floats)
  float* Ppart = (float*)d_ws;
  float* masks = Ppart + NS * P1_F;

  k1_proj<<<256, 256, 0, stream>>>(x, gx_w, gm_w, px_w, pm_w, prx_w, prm_w, Ppart);
  k2_masks<<<64, 64, 0, stream>>>(Ppart, masks);
  k3f<<<512, 256, 0, stream>>>(Ppart, masks, px_b, pm_b, prx_b, prm_b,
                               pfx_w, pfx_b, pfm_w, pfm_b, pb_w, pb_b, out);
}